// Round 5
// baseline (544.925 us; speedup 1.0000x reference)
//
#include <hip/hip_runtime.h>
#include <math.h>

// Problem constants
#define NTOK   32768       // B*S
#define D      2048        // N_EMBED
#define E      64          // NUM_EXPERTS
#define TOPK   8

#define BLOCK  256
#define TM     64          // tokens per block
#define BK     32          // K per chunk == MFMA K
#define NCHUNK (D / BK)    // 64
#define NBLK   (NTOK / TM) // 512

// w_bf layout in d_ws: per chunk c (16384 B): hi frags [0,8192), lo frags [8192,16384)
// frag index = koct*128 + col (col 0..63 router, 64..127 noise), 16 B each
#define WBF_BYTES (NCHUNK * 16384)   // 1 MiB

// LDS layout (bytes): A tile double-buffered ONLY (B goes global->reg)
#define ABUF0   0          // A chunk buf0: hi [0,4096), lo [4096,8192)
#define ABUF1   8192       // buf1: hi/lo
#define LG_OFF  0          // after K loop: float[64][133] (reuses A bufs)
#define LG_STR  133
#define WSK_OFF 34048      // float[2048] staged w_skip (live during K loop only)
#define SP_OFF  42240      // float[64] skip partials
#define SMEM_BYTES 42496

#define TIE_EPS 1e-4f

typedef __bf16 bf16x8 __attribute__((ext_vector_type(8)));
typedef float  f32x4  __attribute__((ext_vector_type(4)));

__device__ __forceinline__ unsigned short f2bf_rne(float f) {
    unsigned int u = __float_as_uint(f);
    u += 0x7FFFu + ((u >> 16) & 1u);
    return (unsigned short)(u >> 16);
}

__device__ __forceinline__ void split_pack8(const float* xv, uint4& hv, uint4& lv) {
    unsigned int h[8], l[8];
#pragma unroll
    for (int j = 0; j < 8; ++j) {
        unsigned short hb = f2bf_rne(xv[j]);
        float hf = __uint_as_float(((unsigned int)hb) << 16);
        unsigned short lb = f2bf_rne(xv[j] - hf);
        h[j] = hb; l[j] = lb;
    }
    hv.x = h[0] | (h[1] << 16); hv.y = h[2] | (h[3] << 16);
    hv.z = h[4] | (h[5] << 16); hv.w = h[6] | (h[7] << 16);
    lv.x = l[0] | (l[1] << 16); lv.y = l[2] | (l[3] << 16);
    lv.z = l[4] | (l[5] << 16); lv.w = l[6] | (l[7] << 16);
}

// ---------------- pre-kernel: convert W (router||noise) to split-bf16 fragment layout ----------
__global__ __launch_bounds__(256) void convert_w_kernel(
    const float* __restrict__ wr, const float* __restrict__ wn, char* __restrict__ wbf)
{
    int u = blockIdx.x * 256 + threadIdx.x;      // 64 chunks * 4 koct * 128 col
    int col  = u & 127;
    int koct = (u >> 7) & 3;
    int c    = u >> 9;
    const float* src = (col < 64)
        ? (wr + (size_t)(c * BK + koct * 8) * E + col)
        : (wn + (size_t)(c * BK + koct * 8) * E + (col - 64));
    float xv[8];
#pragma unroll
    for (int j = 0; j < 8; ++j) xv[j] = src[(size_t)j * E];
    uint4 hv, lv;
    split_pack8(xv, hv, lv);
    char* dst = wbf + (size_t)c * 16384 + (size_t)(koct * 128 + col) * 16;
    *(uint4*)dst = hv;
    *(uint4*)(dst + 8192) = lv;
}

// ---------------- main router kernel: split-bf16 MFMA GEMM, register-pipelined ----------------
__global__ __launch_bounds__(BLOCK, 2) void router_kernel(
    const float* __restrict__ x, const float* __restrict__ eps,
    const char* __restrict__ wbf,
    const float* __restrict__ b_router, const float* __restrict__ b_noise,
    const float* __restrict__ w_skip, const float* __restrict__ b_skip,
    float* __restrict__ out_router, float* __restrict__ out_idx,
    float* __restrict__ out_skip, int* __restrict__ flags, int cap)
{
    __shared__ __attribute__((aligned(16))) char smem[SMEM_BYTES];
    const int tid = threadIdx.x;
    const int tokBase = blockIdx.x * TM;

    const int lane = tid & 63;
    const int wv   = tid >> 6;       // wave id 0..3
    const int q    = lane >> 4;      // k-octet for frag reads
    const int m    = lane & 15;

    // A-staging mapping: thread -> (token, koct)
    const int tokA  = tid >> 2;      // 0..63
    const int koctA = tid & 3;       // 0..3
    const int fragA = (koctA << 6) + (tokA ^ (koctA << 2));   // XOR swizzle
    const float* xptr = x + (size_t)(tokBase + tokA) * D + koctA * 8;

    f32x4 acc[4][2];
#pragma unroll
    for (int tt = 0; tt < 4; ++tt)
#pragma unroll
        for (int cw = 0; cw < 2; ++cw) acc[tt][cw] = (f32x4){0.f, 0.f, 0.f, 0.f};
    float skipAcc = 0.f;

    float* wsk = (float*)(smem + WSK_OFF);

    // B fragments: direct global->register loads (no LDS, no vmcnt drain at barriers)
    auto loadB = [&](int c, uint4* bh, uint4* bl) {
        const char* src = wbf + (size_t)c * 16384;
#pragma unroll
        for (int cw = 0; cw < 2; ++cw) {
            int f = (q << 7) + (wv << 5) + (cw << 4) + m;
            bh[cw] = *(const uint4*)(src + f * 16);
            bl[cw] = *(const uint4*)(src + 8192 + f * 16);
        }
    };

    auto storeA = [&](int buf, float4 a0, float4 a1) {
        float xv[8] = {a0.x, a0.y, a0.z, a0.w, a1.x, a1.y, a1.z, a1.w};
        uint4 hv, lv;
        split_pack8(xv, hv, lv);
        char* ab = smem + (buf ? ABUF1 : ABUF0);
        *(uint4*)(ab + fragA * 16) = hv;
        *(uint4*)(ab + 4096 + fragA * 16) = lv;
    };

    auto skipFma = [&](float4 a0, float4 a1, int c) {
        const float* wk = wsk + c * BK + koctA * 8;
        skipAcc = fmaf(a0.x, wk[0], skipAcc); skipAcc = fmaf(a0.y, wk[1], skipAcc);
        skipAcc = fmaf(a0.z, wk[2], skipAcc); skipAcc = fmaf(a0.w, wk[3], skipAcc);
        skipAcc = fmaf(a1.x, wk[4], skipAcc); skipAcc = fmaf(a1.y, wk[5], skipAcc);
        skipAcc = fmaf(a1.z, wk[6], skipAcc); skipAcc = fmaf(a1.w, wk[7], skipAcc);
    };

    auto compute = [&](int buf, const uint4* bh, const uint4* bl) {
        const char* ab = smem + (buf ? ABUF1 : ABUF0);
        uint4 ah[4], al[4];
#pragma unroll
        for (int tt = 0; tt < 4; ++tt) {
            int f = (q << 6) + (((tt << 4) + m) ^ (q << 2));
            ah[tt] = *(const uint4*)(ab + f * 16);
            al[tt] = *(const uint4*)(ab + 4096 + f * 16);
        }
#pragma unroll
        for (int tt = 0; tt < 4; ++tt)
#pragma unroll
            for (int cw = 0; cw < 2; ++cw) {
                bf16x8 Ah = __builtin_bit_cast(bf16x8, ah[tt]);
                bf16x8 Al = __builtin_bit_cast(bf16x8, al[tt]);
                bf16x8 Bh = __builtin_bit_cast(bf16x8, bh[cw]);
                bf16x8 Bl = __builtin_bit_cast(bf16x8, bl[cw]);
                acc[tt][cw] = __builtin_amdgcn_mfma_f32_16x16x32_bf16(Ah, Bh, acc[tt][cw], 0, 0, 0);
                acc[tt][cw] = __builtin_amdgcn_mfma_f32_16x16x32_bf16(Ah, Bl, acc[tt][cw], 0, 0, 0);
                acc[tt][cw] = __builtin_amdgcn_mfma_f32_16x16x32_bf16(Al, Bh, acc[tt][cw], 0, 0, 0);
            }
    };

    // ---- prologue ----
#pragma unroll
    for (int r = 0; r < 2; ++r) {
        int i4 = tid + 256 * r;
        ((float4*)wsk)[i4] = ((const float4*)w_skip)[i4];
    }
    float4 xq[2][2];                 // xq[slot][0/1]: x for chunk (slot parity)
    xq[0][0] = *(const float4*)(xptr);
    xq[0][1] = *(const float4*)(xptr + 4);
    xq[1][0] = *(const float4*)(xptr + BK);
    xq[1][1] = *(const float4*)(xptr + BK + 4);
    uint4 bh[2], bl[2], bhn[2], bln[2];
    loadB(0, bh, bl);
    storeA(0, xq[0][0], xq[0][1]);
    skipFma(xq[0][0], xq[0][1], 0);
    __syncthreads();

    // ---- K loop: A dbuf in LDS, x PF distance 2, B PF distance 1 (all regs) ----
    for (int c = 0; c < NCHUNK; ++c) {
        if (c + 1 < NCHUNK) loadB(c + 1, bhn, bln);
        float4 xn0, xn1;
        if (c + 2 < NCHUNK) {
            xn0 = *(const float4*)(xptr + (c + 2) * BK);
            xn1 = *(const float4*)(xptr + (c + 2) * BK + 4);
        }
        compute(c & 1, bh, bl);
        if (c + 1 < NCHUNK) {
            storeA((c + 1) & 1, xq[(c + 1) & 1][0], xq[(c + 1) & 1][1]);
            skipFma(xq[(c + 1) & 1][0], xq[(c + 1) & 1][1], c + 1);
        }
        if (c + 2 < NCHUNK) { xq[c & 1][0] = xn0; xq[c & 1][1] = xn1; }
#pragma unroll
        for (int cw = 0; cw < 2; ++cw) { bh[cw] = bhn[cw]; bl[cw] = bln[cw]; }
        __syncthreads();
    }

    // ---- dump accumulators to logits[64][133] (C/D: col=lane&15, row=q*4+reg) ----
    float* lg = (float*)(smem + LG_OFF);
#pragma unroll
    for (int tt = 0; tt < 4; ++tt)
#pragma unroll
        for (int cw = 0; cw < 2; ++cw) {
#pragma unroll
            for (int reg = 0; reg < 4; ++reg) {
                int token = tt * 16 + q * 4 + reg;
                int col = wv * 32 + cw * 16 + m;
                lg[token * LG_STR + col] = acc[tt][cw][reg];
            }
        }

    // skip reduce: threads 4t..4t+3 (adjacent lanes) hold token t partials
    skipAcc += __shfl_xor(skipAcc, 1);
    skipAcc += __shfl_xor(skipAcc, 2);
    if ((tid & 3) == 0) ((float*)(smem + SP_OFF))[tokA] = skipAcc;
    __syncthreads();

    // ---- epilogue: one lane per token ----
    if (tid < 64) {
        const int t = tid;
        const int tok = tokBase + t;
        float* row = lg + t * LG_STR;

        float sv = ((float*)(smem + SP_OFF))[t] + b_skip[0];
        out_skip[tok] = 1.f / (1.f + expf(-sv));

        const float4* epsr = (const float4*)(eps + (size_t)tok * E);
#pragma unroll 4
        for (int e4 = 0; e4 < 16; ++e4) {
            float4 ep = epsr[e4];
            float epv[4] = {ep.x, ep.y, ep.z, ep.w};
#pragma unroll
            for (int u2 = 0; u2 < 4; ++u2) {
                int e = e4 * 4 + u2;
                float lgv = row[e] + b_router[e];
                float nl  = row[64 + e] + b_noise[e];
                float sp  = fmaxf(nl, 0.f) + log1pf(expf(-fabsf(nl)));
                row[e] = lgv + epv[u2] * sp;
            }
        }

        // top-9 (strict '>' => lowest index wins ties; matches lax.top_k)
        float vals[9];
        int idxs[8];
        for (int p = 0; p < 9; ++p) {
            float best = -INFINITY;
            int bi = 0;
            for (int e = 0; e < 64; ++e) {
                float v = row[e];
                if (v > best) { best = v; bi = e; }
            }
            vals[p] = best;
            if (p < 8) idxs[p] = bi;
            row[bi] = -INFINITY;
        }

        float mg = 1e30f;
#pragma unroll
        for (int p = 0; p < 8; ++p) mg = fminf(mg, vals[p] - vals[p + 1]);
        if (mg < TIE_EPS) {
            int slot = atomicAdd(flags, 1);
            if (slot < cap) flags[2 + slot] = tok;
        }

        float mx = vals[0];
        float g[8], s = 0.f;
#pragma unroll
        for (int p = 0; p < 8; ++p) { g[p] = expf(vals[p] - mx); s += g[p]; }
        float inv = 1.f / s;

        float* rrow = row + 64;
#pragma unroll
        for (int e = 0; e < 64; ++e) rrow[e] = 0.f;
#pragma unroll
        for (int p = 0; p < 8; ++p) rrow[idxs[p]] = g[p] * inv;
#pragma unroll
        for (int e4 = 0; e4 < 16; ++e4) {
            float4 o = make_float4(rrow[e4 * 4], rrow[e4 * 4 + 1],
                                   rrow[e4 * 4 + 2], rrow[e4 * 4 + 3]);
            *(float4*)(out_router + (size_t)tok * E + e4 * 4) = o;
        }
        float4 i0 = make_float4((float)idxs[0], (float)idxs[1], (float)idxs[2], (float)idxs[3]);
        float4 i1 = make_float4((float)idxs[4], (float)idxs[5], (float)idxs[6], (float)idxs[7]);
        *(float4*)(out_idx + (size_t)tok * TOPK)     = i0;
        *(float4*)(out_idx + (size_t)tok * TOPK + 4) = i1;
    }
}

// ---------------- f64 fixup: one block per token, 4 waves split K, lane = expert ---------------
__global__ __launch_bounds__(256) void fixup_kernel(
    const float* __restrict__ x, const float* __restrict__ eps,
    const float* __restrict__ w_router, const float* __restrict__ b_router,
    const float* __restrict__ w_noise, const float* __restrict__ b_noise,
    float* __restrict__ out_router, float* __restrict__ out_idx,
    const int* __restrict__ flags, int cap)
{
    __shared__ double smR[4][64];
    __shared__ double smN[4][64];
    __shared__ double noisy[64];
    const int tid  = threadIdx.x;
    const int lane = tid & 63;      // expert
    const int qw   = tid >> 6;      // K quarter

    int count = flags[0];
    if (count > cap) count = cap;

    for (int i = blockIdx.x; i < count; i += gridDim.x) {
        int tok = flags[2 + i];
        const float4* xr4 = (const float4*)(x + (size_t)tok * D + qw * 512);
        const float* wrB = w_router + (size_t)(qw * 512) * E + lane;
        const float* wnB = w_noise  + (size_t)(qw * 512) * E + lane;

        double pr0 = 0, pr1 = 0, pr2 = 0, pr3 = 0;
        double pn0 = 0, pn1 = 0, pn2 = 0, pn3 = 0;
#pragma unroll 2
        for (int it = 0; it < 128; ++it) {
            float4 xv = xr4[it];
            const float* wr = wrB + (size_t)(it * 4) * E;
            const float* wn = wnB + (size_t)(it * 4) * E;
            pr0 += (double)xv.x * (double)wr[0];
            pr1 += (double)xv.y * (double)wr[E];
            pr2 += (double)xv.z * (double)wr[2 * E];
            pr3 += (double)xv.w * (double)wr[3 * E];
            pn0 += (double)xv.x * (double)wn[0];
            pn1 += (double)xv.y * (double)wn[E];
            pn2 += (double)xv.z * (double)wn[2 * E];
            pn3 += (double)xv.w * (double)wn[3 * E];
        }
        smR[qw][lane] = (pr0 + pr1) + (pr2 + pr3);
        smN[qw][lane] = (pn0 + pn1) + (pn2 + pn3);
        __syncthreads();

        if (tid < 64) {
            double lgv = smR[0][tid] + smR[1][tid] + smR[2][tid] + smR[3][tid] + (double)b_router[tid];
            double nl  = smN[0][tid] + smN[1][tid] + smN[2][tid] + smN[3][tid] + (double)b_noise[tid];
            double sp  = fmax(nl, 0.0) + log1p(exp(-fabs(nl)));
            noisy[tid] = lgv + (double)eps[(size_t)tok * E + tid] * sp;
        }
        __syncthreads();

        if (tid == 0) {
            double tmp[64];
            for (int j = 0; j < 64; ++j) tmp[j] = noisy[j];
            double vals[8]; int idxs[8];
            for (int p = 0; p < 8; ++p) {
                double best = -1e300; int bi = 0;
                for (int j = 0; j < 64; ++j)
                    if (tmp[j] > best) { best = tmp[j]; bi = j; }
                vals[p] = best; idxs[p] = bi; tmp[bi] = -1e300;
            }
            double mx = vals[0], s = 0.0, g[8];
            for (int p = 0; p < 8; ++p) { g[p] = exp(vals[p] - mx); s += g[p]; }
            float rowv[64];
            for (int j = 0; j < 64; ++j) rowv[j] = 0.f;
            for (int p = 0; p < 8; ++p) rowv[idxs[p]] = (float)(g[p] / s);
            for (int j = 0; j < 64; ++j) out_router[(size_t)tok * E + j] = rowv[j];
            for (int p = 0; p < 8; ++p) out_idx[(size_t)tok * TOPK + p] = (float)idxs[p];
        }
        __syncthreads();
    }
}

extern "C" void kernel_launch(void* const* d_in, const int* in_sizes, int n_in,
                              void* d_out, int out_size, void* d_ws, size_t ws_size,
                              hipStream_t stream) {
    const float* x        = (const float*)d_in[0];
    const float* eps      = (const float*)d_in[1];
    const float* w_router = (const float*)d_in[2];
    const float* b_router = (const float*)d_in[3];
    const float* w_noise  = (const float*)d_in[4];
    const float* b_noise  = (const float*)d_in[5];
    const float* w_skip   = (const float*)d_in[6];
    const float* b_skip   = (const float*)d_in[7];

    float* out = (float*)d_out;
    float* out_router = out;                           // 32768*64
    float* out_idx    = out + (size_t)NTOK * E;        // 32768*8
    float* out_skip   = out_idx + (size_t)NTOK * TOPK; // 32768

    char* wbf  = (char*)d_ws;
    int* flags = (int*)((char*)d_ws + WBF_BYTES);
    int cap = 0;
    if (ws_size > WBF_BYTES + 16) {
        size_t c = (ws_size - WBF_BYTES - 8) / 4;
        cap = (c > 16384) ? 16384 : (int)c;
    }

    hipMemsetAsync((char*)d_ws + WBF_BYTES, 0, 8, stream);

    convert_w_kernel<<<dim3(128), dim3(256), 0, stream>>>(w_router, w_noise, wbf);

    router_kernel<<<dim3(NBLK), dim3(BLOCK), 0, stream>>>(
        x, eps, wbf, b_router, b_noise, w_skip, b_skip,
        out_router, out_idx, out_skip, flags, cap);

    fixup_kernel<<<dim3(512), dim3(256), 0, stream>>>(
        x, eps, w_router, b_router, w_noise, b_noise,
        out_router, out_idx, flags, cap);
}